// Round 18
// baseline (119.442 us; speedup 1.0000x reference)
//
#include <hip/hip_runtime.h>
#include <math.h>

#pragma clang fp contract(off)

// Problem constants
#define B_   128
#define CI_  16
#define CO_  32
#define H_   32
#define W_   32
#define HO_  30
#define WO_  30
#define P_   900                 // HO*WO
#define CP_  (CO_*P_)            // 28800
#define N_   ((size_t)B_*CP_)    // 3686400 elements per tensor
#define NBLK_CONV (4*30*8)       // stat slots = 960 (UNCHANGED -> stats bitwise identical)
#define WSTRIDE_O 129600         // CI_*P_*9
#define WSTRIDE_C 8100           // P_*9
#define FFC_ (H_*W_)             // 1024  (channel stride in ff)
#define FFB_ (CI_*H_*W_)         // 16384 (batch stride in ff)
#define FFTOT_ (B_*FFB_)         // 2097152 total ff floats

// d_out layout (4*N_ floats): [0,N)=soma, [N,2N)=spike, [2N,3N)=a_new, [3N,4N)=b_new.
// Slot [3N,4N) temporarily holds the f32 conv value; LIF reads it before
// overwriting with b_new.

// async global->LDS. LDS dest is wave-uniform base + lane*width.
typedef __attribute__((address_space(1))) const unsigned int gas_uint;
typedef __attribute__((address_space(3))) unsigned int las_uint;
__device__ __forceinline__ void gload_lds4(const float* g, float* l) {
    __builtin_amdgcn_global_load_lds((gas_uint*)g, (las_uint*)l, 4, 0, 0);
}
__device__ __forceinline__ void gload_lds16(const float* g, float* l) {
    __builtin_amdgcn_global_load_lds((gas_uint*)g, (las_uint*)l, 16, 0, 0);
}

// counted waits (single-wave kernels only: no cross-wave barrier semantics)
#define VW8  asm volatile("s_waitcnt vmcnt(8)" ::: "memory")
#define VW0  asm volatile("s_waitcnt vmcnt(0)" ::: "memory")
#define LK0  asm volatile("s_waitcnt lgkmcnt(0)" ::: "memory")

// ---------------------------------------------------------------------------
// Kernel 1: locally-connected conv — SINGLE-WAVE, BARRIER-FREE, counted
// vmcnt (T4). R17 diagnosis: per-channel __syncthreads = vmcnt(0) made each
// wave drain its OWN just-issued prefetch (200-900 cyc) 16 times; with ~1.4
// waves/SIMD effective nothing hid it; conv pinned at ~65us across all
// geometries. With 64-thr (1-wave) blocks the barrier is unnecessary:
// stage->read ordering within one wave needs only a counted vmcnt wait, and
// LDS visibility needs no s_barrier (race-free by construction -- the thing
// that killed R4/R6 was cross-wave vmcnt+barrier interplay).
//  - each stage = EXACTLY 14 VMEM instrs (10+1 weight gload_lds4, 2+1 ff
//    gload_lds16; exec-masked instrs still issue). vmcnt(8) before
//    compute_c(c) guarantees stage(c) landed (safe for any per-stage count
//    >= 8; the 10 unconditional weight loads bound it), while stage(c+1)'s
//    tail stays in flight across the whole compute phase.
//  - lgkmcnt(0) before re-staging a buffer (its ds_reads retired).
//  - last channel peels with vmcnt(0).
// Geometry/staging/compute/stats = R17 VERBATIM: 64 thr = 8o x 8w x 16b per
// block via thread = 2o x 2w x 4b; grid dim3(16,30,8) = 3840; weight LDS
// 8x76 + k8 plane (w*8+k layout matches staging: R16's lesson); ff 576;
// wk b128 slots all-8-hit-2x = free; weight-sharers 480 apart = 0 mod 8 ->
// same XCD. Stats: same 960x32 f64 slots, same sums, same butterfly ->
// BITWISE identical outputs. Accumulation (c, kh, kw; mul-add, no FMA).
// ---------------------------------------------------------------------------
__global__ __launch_bounds__(64) void conv_kernel(
    const float* __restrict__ ff, const float* __restrict__ weight,
    const float* __restrict__ conv_bias, float* __restrict__ outf,
    double* __restrict__ part_sum, double* __restrict__ part_sumsq)
{
#pragma clang fp contract(off)
    const int tid = threadIdx.x;        // 0..63
    const int og  = tid & 3;            // 0..3
    const int wg2 = (tid >> 2) & 3;     // 0..3
    const int bg  = (tid >> 4) & 3;     // 0..3
    const int wt  = blockIdx.x & 3;     // 0..3
    const int os  = blockIdx.x >> 2;    // 0..3  (8-o slice: o = os*8 ..)
    const int h   = blockIdx.y;         // 0..29
    const int b0  = blockIdx.z * 16;    // 16 batches per block
    const int w0  = wt * 8 + wg2 * 2;
    const bool val = !(wt == 3 && wg2 == 3);
    const int ob  = os * 8;             // global o base

    __shared__ float wgl[2][672];       // 8x76 (608) + k8 plane 608..671
    __shared__ float ffs[2][576];       // [bb*36 + r*12 + cc]

    // ---- c-independent staging offsets (all in-bounds by construction) ----
    int wq_off[11];
#pragma unroll
    for (int q = 0; q < 11; ++q) {
        int m = q * 64 + tid;           // q=10 masked to tid<32 at issue
        int src = 0;
        if (m < 608) {
            int ol = m / 76, r = m - ol * 76;
            if (r < 64) {                       // DATA: layout w*8+k (matches compute)
                int w = r >> 3, k = r & 7;
                int colc = wt * 8 + w; if (colc > 29) colc = 29;   // edge clamp
                src = (ob + ol) * WSTRIDE_O + (h * WO_ + colc) * 9 + k;
            }
        } else if (m < 672) {
            int idx = m - 608, ol = idx >> 3, w = idx & 7;
            int colc = wt * 8 + w; if (colc > 29) colc = 29;
            src = (ob + ol) * WSTRIDE_O + (h * WO_ + colc) * 9 + 8;
        }
        wq_off[q] = src;
    }
    int f_off[3];
#pragma unroll
    for (int q = 0; q < 3; ++q) {
        int d = q * 256 + tid * 4;
        int dd = (d < 576) ? d : 0;
        int bb = dd / 36, rm = dd - bb * 36, r = rm / 12, cc0 = rm - r * 12;
        f_off[q] = (b0 + bb) * FFB_ + (h + r) * W_ + wt * 8 + cc0;  // 16B-aligned
    }

    float acc[2][2][4];                  // [oo][ww][j]
#pragma unroll
    for (int oo = 0; oo < 2; ++oo)
#pragma unroll
        for (int ww = 0; ww < 2; ++ww)
#pragma unroll
            for (int j = 0; j < 4; ++j) acc[oo][ww][j] = 0.f;

    auto stage = [&](int c, int buf) {   // EXACTLY 14 VMEM instructions
        const float* wsrc = weight + c * WSTRIDE_C;
#pragma unroll
        for (int q = 0; q < 10; ++q)
            gload_lds4(wsrc + wq_off[q], &wgl[buf][q * 64]);
        if (tid < 32)
            gload_lds4(wsrc + wq_off[10], &wgl[buf][640]);
#pragma unroll
        for (int q = 0; q < 3; ++q) {
            if (q < 2 || tid < 16) {
                int g = f_off[q] + c * FFC_;
                if (g > FFTOT_ - 4) g = FFTOT_ - 4;  // corner clamp (garbage slots only)
                gload_lds16(ff + g, &ffs[buf][q * 256]);
            }
        }
    };

    auto compute_c = [&](int buf) {
        float wk[2][2][9];
#pragma unroll
        for (int oo = 0; oo < 2; ++oo)
#pragma unroll
            for (int ww = 0; ww < 2; ++ww) {
                const int ol = oo * 4 + og, w = wg2 * 2 + ww;     // o-interleave
                const float* wp = &wgl[buf][ol * 76 + w * 8];     // 304B stride, 16B-aligned
                const float4 a = *reinterpret_cast<const float4*>(wp);
                const float4 b = *reinterpret_cast<const float4*>(wp + 4);
                wk[oo][ww][0] = a.x; wk[oo][ww][1] = a.y; wk[oo][ww][2] = a.z; wk[oo][ww][3] = a.w;
                wk[oo][ww][4] = b.x; wk[oo][ww][5] = b.y; wk[oo][ww][6] = b.z; wk[oo][ww][7] = b.w;
                wk[oo][ww][8] = wgl[buf][608 + ol * 8 + w];
            }
#pragma unroll
        for (int j = 0; j < 4; ++j) {
            const int bb = bg * 4 + j;
            float fr[3][4];
#pragma unroll
            for (int r = 0; r < 3; ++r) {
                const float2 u = *reinterpret_cast<const float2*>(&ffs[buf][bb * 36 + r * 12 + wg2 * 2]);
                const float2 v = *reinterpret_cast<const float2*>(&ffs[buf][bb * 36 + r * 12 + wg2 * 2 + 2]);
                fr[r][0] = u.x; fr[r][1] = u.y; fr[r][2] = v.x; fr[r][3] = v.y;
            }
#pragma unroll
            for (int oo = 0; oo < 2; ++oo)
#pragma unroll
                for (int ww = 0; ww < 2; ++ww) {
                    float a = acc[oo][ww][j];
#pragma unroll
                    for (int kh = 0; kh < 3; ++kh)
#pragma unroll
                        for (int kw = 0; kw < 3; ++kw) {
                            float prod = wk[oo][ww][kh * 3 + kw] * fr[kh][ww + kw];
                            a = a + prod;      // no FMA, (c,kh,kw) order
                        }
                    acc[oo][ww][j] = a;
                }
        }
    };

    // barrier-free counted-vmcnt pipeline (single wave):
    stage(0, 0);
    stage(1, 1);
    for (int cs = 0; cs < 14; cs += 2) {            // channels 0..13
        VW8;                         // stage(cs) landed; stage(cs+1) in flight
        compute_c(0);
        LK0;                         // buf0 ds_reads retired before re-stage
        stage(cs + 2, 0);
        VW8;                         // stage(cs+1) landed
        compute_c(1);
        LK0;
        stage(cs + 3, 1);
    }
    VW8;                             // stage(14) landed (<=8 of stage(15) remain)
    compute_c(0);                    // channel 14
    VW0;                             // stage(15) fully landed
    compute_c(1);                    // channel 15

    // epilogue: bias, park conv values, exact f64 per-slot per-channel stats
    double s1[2] = {0.0, 0.0}, s2[2] = {0.0, 0.0};
    if (val) {
#pragma unroll
        for (int oo = 0; oo < 2; ++oo) {
            const int o = ob + oo * 4 + og;
            const int pidx = o * P_ + h * WO_ + w0;
            const float2 bi = *reinterpret_cast<const float2*>(conv_bias + pidx);
#pragma unroll
            for (int j = 0; j < 4; ++j) {
                const int b = b0 + bg * 4 + j;
                const size_t n = (size_t)b * CP_ + (size_t)pidx;
                float v0 = acc[oo][0][j] + bi.x;     // f32, same as ref
                float v1 = acc[oo][1][j] + bi.y;
                *reinterpret_cast<float2*>(outf + 3 * N_ + n) = make_float2(v0, v1);
                double d0 = (double)v0, d1 = (double)v1;
                s1[oo] += d0; s2[oo] += d0 * d0;
                s1[oo] += d1; s2[oo] += d1 * d1;
            }
        }
    }
    // deterministic reduce over the 16 lanes (stride 4) sharing og
#pragma unroll
    for (int d = 4; d < 64; d <<= 1) {
#pragma unroll
        for (int oo = 0; oo < 2; ++oo) {
            s1[oo] += __shfl_xor(s1[oo], d);
            s2[oo] += __shfl_xor(s2[oo], d);
        }
    }
    if ((tid & 60) == 0) {               // wg2==0 && bg==0: tid 0..3
        int blk = (blockIdx.z * 30 + blockIdx.y) * 4 + wt;   // 0..959 (same slots)
#pragma unroll
        for (int oo = 0; oo < 2; ++oo) {
            const int o = ob + oo * 4 + og;
            part_sum  [blk * CO_ + o] = s1[oo];
            part_sumsq[blk * CO_ + o] = s2[oo];
        }
    }
}

// ---------------------------------------------------------------------------
// Kernel 2: BN finalize — deterministic f64 reduction of partials (960
// slots), then f32 mean / inv_std per channel. UNCHANGED.
// ---------------------------------------------------------------------------
__global__ __launch_bounds__(256) void bn_finalize(
    const double* __restrict__ part_sum, const double* __restrict__ part_sumsq,
    float* __restrict__ Mb)
{
#pragma clang fp contract(off)
    const int o = blockIdx.x;
    const int tid = threadIdx.x;
    double s1 = 0.0, s2 = 0.0;
    for (int i = tid; i < NBLK_CONV; i += 256) {
        s1 += part_sum[i * CO_ + o];
        s2 += part_sumsq[i * CO_ + o];
    }
    __shared__ double r1[256], r2[256];
    r1[tid] = s1; r2[tid] = s2;
    __syncthreads();
    for (int s = 128; s > 0; s >>= 1) {
        if (tid < s) { r1[tid] += r1[tid + s]; r2[tid] += r2[tid + s]; }
        __syncthreads();
    }
    if (tid == 0) {
        const double cnt = (double)(B_ * (size_t)P_);
        double mean = r1[0] / cnt;
        float meanf = (float)mean;
        double md = (double)meanf;
        double var = r2[0] / cnt - 2.0 * md * (r1[0] / cnt) + md * md;
        float varf = (float)var;
        float invf = 1.0f / sqrtf(varf + 1e-5f);
        Mb[o]       = meanf;
        Mb[CO_ + o] = invf;
    }
}

// ---------------------------------------------------------------------------
// Kernel 3: fused recurrent-bmm + LIF. R15 VERBATIM (best measured lif):
// 2 batches per barrier round, 4 spike tiles (16 KB), register prefetch,
// lgkmcnt(0)-only barrier; 1024 thr = 32 i x 32 p; XCD-grouped grid 512.
// ---------------------------------------------------------------------------
__global__ __launch_bounds__(1024) void lif_rec_kernel(
    float* __restrict__ outf, const float* __restrict__ local_rec,
    const float* __restrict__ tau_m, const float* __restrict__ tau_adp,
    const float* __restrict__ tau_a, const float* __restrict__ Mb,
    const float* __restrict__ gamma, const float* __restrict__ beta,
    const float* __restrict__ fb, const float* __restrict__ soma_t,
    const float* __restrict__ spk_t, const float* __restrict__ a_curr,
    const float* __restrict__ b_t)
{
#pragma clang fp contract(off)
    const int D    = blockIdx.x;
    const int pt8  = D & 7;
    const int rest = D >> 3;
    const int by   = rest & 15;
    const int ptq  = rest >> 4;          // 0..3
    const int pt   = ptq * 8 + pt8;      // 0..31
    if (pt >= 29) return;                // 29 p-tiles cover P_=900

    const int tid = threadIdx.x;
    const int pp  = tid & 31;
    const int i   = tid >> 5;            // channel 0..31
    const int p   = pt * 32 + pp;
    const bool pv = (p < P_);
    const int b0  = by * 8;

    float L[32];
    float meanf = 0.f, invf = 0.f, gm = 0.f, be = 0.f;
    float al = 0.f, rh = 0.f, et = 0.f;
    int rem = 0;
    if (pv) {
        const float4* lp = reinterpret_cast<const float4*>(local_rec + (size_t)p * (CO_ * CO_) + i * CO_);
#pragma unroll
        for (int q = 0; q < 8; ++q) {
            float4 v = lp[q];
            L[4 * q] = v.x; L[4 * q + 1] = v.y; L[4 * q + 2] = v.z; L[4 * q + 3] = v.w;
        }
        rem = i * P_ + p;
        meanf = Mb[i]; invf = Mb[CO_ + i];
        gm = gamma[i]; be = beta[i];
        // identical f32 ops to the original tau table: f32 divide then f32 exp
        al = expf(-0.5f / tau_m[rem]);
        rh = expf(-0.5f / tau_adp[rem]);
        et = expf(-0.5f / tau_a[rem]);
    }
    const float omr = 1.0f - rh;

    __shared__ float sp[4][CO_][32];     // 16 KB: two double-buffered tile PAIRS

    // prologue: operands for batches b0, b0+1
    size_t n = (size_t)b0 * CP_ + (size_t)rem;
    float sk0 = 0.f, cv0 = 0.f, bt0 = 0.f, ac0 = 0.f, fb0 = 0.f, so0 = 0.f;
    float sk1 = 0.f, cv1 = 0.f, bt1 = 0.f, ac1 = 0.f, fb1 = 0.f, so1 = 0.f;
    if (pv) {
        sk0 = spk_t[n];       cv0 = outf[3 * N_ + n];       bt0 = b_t[n];
        ac0 = a_curr[n];      fb0 = fb[n];                  so0 = soma_t[n];
        const size_t n1 = n + (size_t)CP_;
        sk1 = spk_t[n1];      cv1 = outf[3 * N_ + n1];      bt1 = b_t[n1];
        ac1 = a_curr[n1];     fb1 = fb[n1];                 so1 = soma_t[n1];
    }

#pragma unroll
    for (int r = 0; r < 4; ++r) {
        const int t0 = (r & 1) * 2;      // literal after unroll
        if (pv) {
            sp[t0][i][pp]     = sk0;
            sp[t0 + 1][i][pp] = sk1;
        }
        // prefetch operands for batches 2r+2, 2r+3 BEFORE the barrier
        float sk0n = 0.f, cv0n = 0.f, bt0n = 0.f, ac0n = 0.f, fb0n = 0.f, so0n = 0.f;
        float sk1n = 0.f, cv1n = 0.f, bt1n = 0.f, ac1n = 0.f, fb1n = 0.f, so1n = 0.f;
        if (r < 3 && pv) {
            const size_t n2 = n + (size_t)(2 * CP_);
            const size_t n3 = n + (size_t)(3 * CP_);
            sk0n = spk_t[n2];  cv0n = outf[3 * N_ + n2];  bt0n = b_t[n2];
            ac0n = a_curr[n2]; fb0n = fb[n2];             so0n = soma_t[n2];
            sk1n = spk_t[n3];  cv1n = outf[3 * N_ + n3];  bt1n = b_t[n3];
            ac1n = a_curr[n3]; fb1n = fb[n3];             so1n = soma_t[n3];
        }
        asm volatile("s_waitcnt lgkmcnt(0)\n\ts_barrier" ::: "memory");
        if (pv) {
            // ---- batch 2r ----
            {
                float rec = 0.f;
#pragma unroll
                for (int j = 0; j < CO_; ++j) {
                    float prod = L[j] * sp[t0][j][pp];
                    rec = rec + prod;
                }
                float t  = cv0 - meanf;
                float x  = t * invf;
                float xg = x * gm;
                float cx = xg + be;
                cx = cx + rec;
                float rb  = rh * bt0;
                float os  = omr * sk0;
                float bn  = rb + os;
                float tb = 1.8f * bn;
                float th = 0.1f + tb;
                float ea = et * ac0;
                float an = ea + fb0;
                float sg = 1.0f / (1.0f + expf(-an));
                float as = al * so0;
                float s5 = sg - 0.5f;
                float u1 = as + s5;
                float u2 = u1 + cx;
                float ts = th * sk0;
                float sn = u2 - ts;
                outf[n]          = sn;
                outf[N_ + n]     = ((sn - th) > 0.0f) ? 1.f : 0.f;
                outf[2 * N_ + n] = an;
                outf[3 * N_ + n] = bn;
            }
            // ---- batch 2r+1 ----
            {
                const size_t n1 = n + (size_t)CP_;
                float rec = 0.f;
#pragma unroll
                for (int j = 0; j < CO_; ++j) {
                    float prod = L[j] * sp[t0 + 1][j][pp];
                    rec = rec + prod;
                }
                float t  = cv1 - meanf;
                float x  = t * invf;
                float xg = x * gm;
                float cx = xg + be;
                cx = cx + rec;
                float rb  = rh * bt1;
                float os  = omr * sk1;
                float bn  = rb + os;
                float tb = 1.8f * bn;
                float th = 0.1f + tb;
                float ea = et * ac1;
                float an = ea + fb1;
                float sg = 1.0f / (1.0f + expf(-an));
                float as = al * so1;
                float s5 = sg - 0.5f;
                float u1 = as + s5;
                float u2 = u1 + cx;
                float ts = th * sk1;
                float sn = u2 - ts;
                outf[n1]          = sn;
                outf[N_ + n1]     = ((sn - th) > 0.0f) ? 1.f : 0.f;
                outf[2 * N_ + n1] = an;
                outf[3 * N_ + n1] = bn;
            }
        }
        sk0 = sk0n; cv0 = cv0n; bt0 = bt0n; ac0 = ac0n; fb0 = fb0n; so0 = so0n;
        sk1 = sk1n; cv1 = cv1n; bt1 = bt1n; ac1 = ac1n; fb1 = fb1n; so1 = so1n;
        n += (size_t)(2 * CP_);
    }
}

extern "C" void kernel_launch(void* const* d_in, const int* in_sizes, int n_in,
                              void* d_out, int out_size, void* d_ws, size_t ws_size,
                              hipStream_t stream)
{
    const float* ff        = (const float*)d_in[0];
    const float* fb        = (const float*)d_in[1];
    const float* soma_t    = (const float*)d_in[2];
    const float* spk_t     = (const float*)d_in[3];
    const float* a_curr    = (const float*)d_in[4];
    const float* b_t       = (const float*)d_in[5];
    const float* weight    = (const float*)d_in[6];
    const float* conv_bias = (const float*)d_in[7];
    const float* local_rec = (const float*)d_in[8];
    const float* gamma     = (const float*)d_in[9];
    const float* beta      = (const float*)d_in[10];
    const float* tau_m     = (const float*)d_in[11];
    const float* tau_adp   = (const float*)d_in[12];
    const float* tau_a     = (const float*)d_in[13];

    // ws: f64 partials then Mb (~0.5 MB total)
    double* part_sum = (double*)d_ws;                       // NBLK_CONV*CO_
    double* part_sq  = part_sum + (size_t)NBLK_CONV * CO_;  // NBLK_CONV*CO_
    float*  Mb       = (float*)(part_sq + (size_t)NBLK_CONV * CO_);  // 64

    float* outf = (float*)d_out;

    conv_kernel<<<dim3(16, 30, 8), 64, 0, stream>>>(
        ff, weight, conv_bias, outf, part_sum, part_sq);
    bn_finalize<<<dim3(CO_), 256, 0, stream>>>(part_sum, part_sq, Mb);
    lif_rec_kernel<<<dim3(512), 1024, 0, stream>>>(
        outf, local_rec, tau_m, tau_adp, tau_a, Mb, gamma, beta,
        fb, soma_t, spk_t, a_curr, b_t);
}

// Round 19
// 100.945 us; speedup vs baseline: 1.1832x; 1.1832x over previous
//
#include <hip/hip_runtime.h>
#include <math.h>

#pragma clang fp contract(off)

// Problem constants
#define B_   128
#define CI_  16
#define CO_  32
#define H_   32
#define W_   32
#define HO_  30
#define WO_  30
#define P_   900                 // HO*WO
#define CP_  (CO_*P_)            // 28800
#define N_   ((size_t)B_*CP_)    // 3686400 elements per tensor
#define NBLK_CONV (4*30*8)       // stat slots = 960 (UNCHANGED -> stats bitwise identical)
#define WSTRIDE_O 129600         // CI_*P_*9
#define WSTRIDE_C 8100           // P_*9
#define FFC_ (H_*W_)             // 1024  (channel stride in ff)
#define FFB_ (CI_*H_*W_)         // 16384 (batch stride in ff)
#define FFTOT_ (B_*FFB_)         // 2097152 total ff floats

// d_out layout (4*N_ floats): [0,N)=soma, [N,2N)=spike, [2N,3N)=a_new, [3N,4N)=b_new.
// Slot [3N,4N) temporarily holds the f32 conv value; LIF reads it before
// overwriting with b_new.

// async global->LDS. LDS dest is wave-uniform base + lane*width.
typedef __attribute__((address_space(1))) const unsigned int gas_uint;
typedef __attribute__((address_space(3))) unsigned int las_uint;
__device__ __forceinline__ void gload_lds4(const float* g, float* l) {
    __builtin_amdgcn_global_load_lds((gas_uint*)g, (las_uint*)l, 4, 0, 0);
}
__device__ __forceinline__ void gload_lds16(const float* g, float* l) {
    __builtin_amdgcn_global_load_lds((gas_uint*)g, (las_uint*)l, 16, 0, 0);
}

// ---------------------------------------------------------------------------
// Kernel 1: locally-connected conv. R17 body VERBATIM (champion conv, 65us,
// passing) with ONE change: XCD/temporal-locality dispatch remap.
// R17 FETCH accounting: minimum = weights 8.3MB + ff 8MB = 16MB; measured
// 57MB. Cause: the 32 sharers of one (wt,h) group (8 z-blocks same weights
// x 4 os-blocks same ff) were 480 apart in dispatch order -> lines evicted
// between sharers -> HBM misses (~900cy) landing on the per-channel vmcnt(0)
// barrier drains. (R18 corroborates: skewing co-residency pushed FETCH to
// 81MB and dur to 85us.)
// Remap: 1-D grid 3840, id = g3*256 + m*8 + gl, where G = g3*8+gl is the
// (wt,h) group (0..119; wt=G&3, h=G>>2) and m = os+4z (0..31). All 32
// sharers = gl (mod 8) -> SAME XCD, spanning 256 consecutive ids -> tight
// temporal co-residency. Group working set 4x36.9(wgt)+8x36.9(ff) = 443KB
// << 4MB L2. Stat slot blk = (z*30+h)*4+wt unchanged -> same 960 slots,
// same sums, same butterfly -> BITWISE identical outputs.
// Body: 64 thr = 8o x 8w x 16b (thread = 2o x 2w x 4b), weight LDS 8x76 +
// k8 plane (w*8+k layout matches staging -- R16 lesson), ff 576; wk b128
// slots all-8-hit-2x = free; 2-deep dbuf + __syncthreads.
// NOTE (R4/R6/R18 lessons): no VGPR cap, no pointer rotation, no barrier-
// free counted-vmcnt (R18: VGPR 136 + FETCH 81MB), 2-deep only.
// ---------------------------------------------------------------------------
__global__ __launch_bounds__(64) void conv_kernel(
    const float* __restrict__ ff, const float* __restrict__ weight,
    const float* __restrict__ conv_bias, float* __restrict__ outf,
    double* __restrict__ part_sum, double* __restrict__ part_sumsq)
{
#pragma clang fp contract(off)
    const int tid = threadIdx.x;        // 0..63
    const int og  = tid & 3;            // 0..3
    const int wg2 = (tid >> 2) & 3;     // 0..3
    const int bg  = (tid >> 4) & 3;     // 0..3
    // ---- XCD/temporal remap decode ----
    const int D   = blockIdx.x;         // 0..3839
    const int gl  = D & 7;
    const int rr  = D >> 3;
    const int m   = rr & 31;            // 0..31
    const int g3  = rr >> 5;            // 0..14
    const int G   = g3 * 8 + gl;        // 0..119 (wt,h) group
    const int wt  = G & 3;              // 0..3
    const int h   = G >> 2;             // 0..29
    const int os  = m & 3;              // 0..3  (8-o slice)
    const int zb  = m >> 2;             // 0..7
    const int b0  = zb * 16;            // 16 batches per block
    const int w0  = wt * 8 + wg2 * 2;
    const bool val = !(wt == 3 && wg2 == 3);
    const int ob  = os * 8;             // global o base

    __shared__ float wgl[2][672];       // 8x76 (608) + k8 plane 608..671
    __shared__ float ffs[2][576];       // [bb*36 + r*12 + cc]

    // ---- c-independent staging offsets (all in-bounds by construction) ----
    int wq_off[11];
#pragma unroll
    for (int q = 0; q < 11; ++q) {
        int mm = q * 64 + tid;          // q=10 masked to tid<32 at issue
        int src = 0;
        if (mm < 608) {
            int ol = mm / 76, r = mm - ol * 76;
            if (r < 64) {                       // DATA: layout w*8+k (matches compute)
                int w = r >> 3, k = r & 7;
                int colc = wt * 8 + w; if (colc > 29) colc = 29;   // edge clamp
                src = (ob + ol) * WSTRIDE_O + (h * WO_ + colc) * 9 + k;
            }
        } else if (mm < 672) {
            int idx = mm - 608, ol = idx >> 3, w = idx & 7;
            int colc = wt * 8 + w; if (colc > 29) colc = 29;
            src = (ob + ol) * WSTRIDE_O + (h * WO_ + colc) * 9 + 8;
        }
        wq_off[q] = src;
    }
    int f_off[3];
#pragma unroll
    for (int q = 0; q < 3; ++q) {
        int d = q * 256 + tid * 4;
        int dd = (d < 576) ? d : 0;
        int bb = dd / 36, rm = dd - bb * 36, r = rm / 12, cc0 = rm - r * 12;
        f_off[q] = (b0 + bb) * FFB_ + (h + r) * W_ + wt * 8 + cc0;  // 16B-aligned
    }

    float acc[2][2][4];                  // [oo][ww][j]
#pragma unroll
    for (int oo = 0; oo < 2; ++oo)
#pragma unroll
        for (int ww = 0; ww < 2; ++ww)
#pragma unroll
            for (int j = 0; j < 4; ++j) acc[oo][ww][j] = 0.f;

    auto stage = [&](int c, int buf) {
        const float* wsrc = weight + c * WSTRIDE_C;
#pragma unroll
        for (int q = 0; q < 10; ++q)
            gload_lds4(wsrc + wq_off[q], &wgl[buf][q * 64]);
        if (tid < 32)
            gload_lds4(wsrc + wq_off[10], &wgl[buf][640]);
#pragma unroll
        for (int q = 0; q < 3; ++q) {
            if (q < 2 || tid < 16) {
                int g = f_off[q] + c * FFC_;
                if (g > FFTOT_ - 4) g = FFTOT_ - 4;  // corner clamp (garbage slots only)
                gload_lds16(ff + g, &ffs[buf][q * 256]);
            }
        }
    };

    auto compute_c = [&](int buf) {
        float wk[2][2][9];
#pragma unroll
        for (int oo = 0; oo < 2; ++oo)
#pragma unroll
            for (int ww = 0; ww < 2; ++ww) {
                const int ol = oo * 4 + og, w = wg2 * 2 + ww;     // o-interleave
                const float* wp = &wgl[buf][ol * 76 + w * 8];     // 304B stride, 16B-aligned
                const float4 a = *reinterpret_cast<const float4*>(wp);
                const float4 b = *reinterpret_cast<const float4*>(wp + 4);
                wk[oo][ww][0] = a.x; wk[oo][ww][1] = a.y; wk[oo][ww][2] = a.z; wk[oo][ww][3] = a.w;
                wk[oo][ww][4] = b.x; wk[oo][ww][5] = b.y; wk[oo][ww][6] = b.z; wk[oo][ww][7] = b.w;
                wk[oo][ww][8] = wgl[buf][608 + ol * 8 + w];
            }
#pragma unroll
        for (int j = 0; j < 4; ++j) {
            const int bb = bg * 4 + j;
            float fr[3][4];
#pragma unroll
            for (int r = 0; r < 3; ++r) {
                const float2 u = *reinterpret_cast<const float2*>(&ffs[buf][bb * 36 + r * 12 + wg2 * 2]);
                const float2 v = *reinterpret_cast<const float2*>(&ffs[buf][bb * 36 + r * 12 + wg2 * 2 + 2]);
                fr[r][0] = u.x; fr[r][1] = u.y; fr[r][2] = v.x; fr[r][3] = v.y;
            }
#pragma unroll
            for (int oo = 0; oo < 2; ++oo)
#pragma unroll
                for (int ww = 0; ww < 2; ++ww) {
                    float a = acc[oo][ww][j];
#pragma unroll
                    for (int kh = 0; kh < 3; ++kh)
#pragma unroll
                        for (int kw = 0; kw < 3; ++kw) {
                            float prod = wk[oo][ww][kh * 3 + kw] * fr[kh][ww + kw];
                            a = a + prod;      // no FMA, (c,kh,kw) order
                        }
                    acc[oo][ww][j] = a;
                }
        }
    };

    stage(0, 0);
    __syncthreads();
    for (int cs = 0; cs < CI_; cs += 2) {
        if (cs + 1 < CI_) stage(cs + 1, 1);   // prefetch overlaps compute
        compute_c(0);
        __syncthreads();
        if (cs + 2 < CI_) stage(cs + 2, 0);
        compute_c(1);
        __syncthreads();
    }

    // epilogue: bias, park conv values, exact f64 per-slot per-channel stats
    double s1[2] = {0.0, 0.0}, s2[2] = {0.0, 0.0};
    if (val) {
#pragma unroll
        for (int oo = 0; oo < 2; ++oo) {
            const int o = ob + oo * 4 + og;
            const int pidx = o * P_ + h * WO_ + w0;
            const float2 bi = *reinterpret_cast<const float2*>(conv_bias + pidx);
#pragma unroll
            for (int j = 0; j < 4; ++j) {
                const int b = b0 + bg * 4 + j;
                const size_t n = (size_t)b * CP_ + (size_t)pidx;
                float v0 = acc[oo][0][j] + bi.x;     // f32, same as ref
                float v1 = acc[oo][1][j] + bi.y;
                *reinterpret_cast<float2*>(outf + 3 * N_ + n) = make_float2(v0, v1);
                double d0 = (double)v0, d1 = (double)v1;
                s1[oo] += d0; s2[oo] += d0 * d0;
                s1[oo] += d1; s2[oo] += d1 * d1;
            }
        }
    }
    // deterministic reduce over the 16 lanes (stride 4) sharing og
#pragma unroll
    for (int d = 4; d < 64; d <<= 1) {
#pragma unroll
        for (int oo = 0; oo < 2; ++oo) {
            s1[oo] += __shfl_xor(s1[oo], d);
            s2[oo] += __shfl_xor(s2[oo], d);
        }
    }
    if ((tid & 60) == 0) {               // wg2==0 && bg==0: tid 0..3
        int blk = (zb * 30 + h) * 4 + wt;            // same 0..959 slots as R17
#pragma unroll
        for (int oo = 0; oo < 2; ++oo) {
            const int o = ob + oo * 4 + og;
            part_sum  [blk * CO_ + o] = s1[oo];
            part_sumsq[blk * CO_ + o] = s2[oo];
        }
    }
}

// ---------------------------------------------------------------------------
// Kernel 2: BN finalize — deterministic f64 reduction of partials (960
// slots), then f32 mean / inv_std per channel. UNCHANGED.
// ---------------------------------------------------------------------------
__global__ __launch_bounds__(256) void bn_finalize(
    const double* __restrict__ part_sum, const double* __restrict__ part_sumsq,
    float* __restrict__ Mb)
{
#pragma clang fp contract(off)
    const int o = blockIdx.x;
    const int tid = threadIdx.x;
    double s1 = 0.0, s2 = 0.0;
    for (int i = tid; i < NBLK_CONV; i += 256) {
        s1 += part_sum[i * CO_ + o];
        s2 += part_sumsq[i * CO_ + o];
    }
    __shared__ double r1[256], r2[256];
    r1[tid] = s1; r2[tid] = s2;
    __syncthreads();
    for (int s = 128; s > 0; s >>= 1) {
        if (tid < s) { r1[tid] += r1[tid + s]; r2[tid] += r2[tid + s]; }
        __syncthreads();
    }
    if (tid == 0) {
        const double cnt = (double)(B_ * (size_t)P_);
        double mean = r1[0] / cnt;
        float meanf = (float)mean;
        double md = (double)meanf;
        double var = r2[0] / cnt - 2.0 * md * (r1[0] / cnt) + md * md;
        float varf = (float)var;
        float invf = 1.0f / sqrtf(varf + 1e-5f);
        Mb[o]       = meanf;
        Mb[CO_ + o] = invf;
    }
}

// ---------------------------------------------------------------------------
// Kernel 3: fused recurrent-bmm + LIF. R15 VERBATIM (best measured lif):
// 2 batches per barrier round, 4 spike tiles (16 KB), register prefetch,
// lgkmcnt(0)-only barrier; 1024 thr = 32 i x 32 p; XCD-grouped grid 512.
// ---------------------------------------------------------------------------
__global__ __launch_bounds__(1024) void lif_rec_kernel(
    float* __restrict__ outf, const float* __restrict__ local_rec,
    const float* __restrict__ tau_m, const float* __restrict__ tau_adp,
    const float* __restrict__ tau_a, const float* __restrict__ Mb,
    const float* __restrict__ gamma, const float* __restrict__ beta,
    const float* __restrict__ fb, const float* __restrict__ soma_t,
    const float* __restrict__ spk_t, const float* __restrict__ a_curr,
    const float* __restrict__ b_t)
{
#pragma clang fp contract(off)
    const int D    = blockIdx.x;
    const int pt8  = D & 7;
    const int rest = D >> 3;
    const int by   = rest & 15;
    const int ptq  = rest >> 4;          // 0..3
    const int pt   = ptq * 8 + pt8;      // 0..31
    if (pt >= 29) return;                // 29 p-tiles cover P_=900

    const int tid = threadIdx.x;
    const int pp  = tid & 31;
    const int i   = tid >> 5;            // channel 0..31
    const int p   = pt * 32 + pp;
    const bool pv = (p < P_);
    const int b0  = by * 8;

    float L[32];
    float meanf = 0.f, invf = 0.f, gm = 0.f, be = 0.f;
    float al = 0.f, rh = 0.f, et = 0.f;
    int rem = 0;
    if (pv) {
        const float4* lp = reinterpret_cast<const float4*>(local_rec + (size_t)p * (CO_ * CO_) + i * CO_);
#pragma unroll
        for (int q = 0; q < 8; ++q) {
            float4 v = lp[q];
            L[4 * q] = v.x; L[4 * q + 1] = v.y; L[4 * q + 2] = v.z; L[4 * q + 3] = v.w;
        }
        rem = i * P_ + p;
        meanf = Mb[i]; invf = Mb[CO_ + i];
        gm = gamma[i]; be = beta[i];
        // identical f32 ops to the original tau table: f32 divide then f32 exp
        al = expf(-0.5f / tau_m[rem]);
        rh = expf(-0.5f / tau_adp[rem]);
        et = expf(-0.5f / tau_a[rem]);
    }
    const float omr = 1.0f - rh;

    __shared__ float sp[4][CO_][32];     // 16 KB: two double-buffered tile PAIRS

    // prologue: operands for batches b0, b0+1
    size_t n = (size_t)b0 * CP_ + (size_t)rem;
    float sk0 = 0.f, cv0 = 0.f, bt0 = 0.f, ac0 = 0.f, fb0 = 0.f, so0 = 0.f;
    float sk1 = 0.f, cv1 = 0.f, bt1 = 0.f, ac1 = 0.f, fb1 = 0.f, so1 = 0.f;
    if (pv) {
        sk0 = spk_t[n];       cv0 = outf[3 * N_ + n];       bt0 = b_t[n];
        ac0 = a_curr[n];      fb0 = fb[n];                  so0 = soma_t[n];
        const size_t n1 = n + (size_t)CP_;
        sk1 = spk_t[n1];      cv1 = outf[3 * N_ + n1];      bt1 = b_t[n1];
        ac1 = a_curr[n1];     fb1 = fb[n1];                 so1 = soma_t[n1];
    }

#pragma unroll
    for (int r = 0; r < 4; ++r) {
        const int t0 = (r & 1) * 2;      // literal after unroll
        if (pv) {
            sp[t0][i][pp]     = sk0;
            sp[t0 + 1][i][pp] = sk1;
        }
        // prefetch operands for batches 2r+2, 2r+3 BEFORE the barrier
        float sk0n = 0.f, cv0n = 0.f, bt0n = 0.f, ac0n = 0.f, fb0n = 0.f, so0n = 0.f;
        float sk1n = 0.f, cv1n = 0.f, bt1n = 0.f, ac1n = 0.f, fb1n = 0.f, so1n = 0.f;
        if (r < 3 && pv) {
            const size_t n2 = n + (size_t)(2 * CP_);
            const size_t n3 = n + (size_t)(3 * CP_);
            sk0n = spk_t[n2];  cv0n = outf[3 * N_ + n2];  bt0n = b_t[n2];
            ac0n = a_curr[n2]; fb0n = fb[n2];             so0n = soma_t[n2];
            sk1n = spk_t[n3];  cv1n = outf[3 * N_ + n3];  bt1n = b_t[n3];
            ac1n = a_curr[n3]; fb1n = fb[n3];             so1n = soma_t[n3];
        }
        asm volatile("s_waitcnt lgkmcnt(0)\n\ts_barrier" ::: "memory");
        if (pv) {
            // ---- batch 2r ----
            {
                float rec = 0.f;
#pragma unroll
                for (int j = 0; j < CO_; ++j) {
                    float prod = L[j] * sp[t0][j][pp];
                    rec = rec + prod;
                }
                float t  = cv0 - meanf;
                float x  = t * invf;
                float xg = x * gm;
                float cx = xg + be;
                cx = cx + rec;
                float rb  = rh * bt0;
                float os  = omr * sk0;
                float bn  = rb + os;
                float tb = 1.8f * bn;
                float th = 0.1f + tb;
                float ea = et * ac0;
                float an = ea + fb0;
                float sg = 1.0f / (1.0f + expf(-an));
                float as = al * so0;
                float s5 = sg - 0.5f;
                float u1 = as + s5;
                float u2 = u1 + cx;
                float ts = th * sk0;
                float sn = u2 - ts;
                outf[n]          = sn;
                outf[N_ + n]     = ((sn - th) > 0.0f) ? 1.f : 0.f;
                outf[2 * N_ + n] = an;
                outf[3 * N_ + n] = bn;
            }
            // ---- batch 2r+1 ----
            {
                const size_t n1 = n + (size_t)CP_;
                float rec = 0.f;
#pragma unroll
                for (int j = 0; j < CO_; ++j) {
                    float prod = L[j] * sp[t0 + 1][j][pp];
                    rec = rec + prod;
                }
                float t  = cv1 - meanf;
                float x  = t * invf;
                float xg = x * gm;
                float cx = xg + be;
                cx = cx + rec;
                float rb  = rh * bt1;
                float os  = omr * sk1;
                float bn  = rb + os;
                float tb = 1.8f * bn;
                float th = 0.1f + tb;
                float ea = et * ac1;
                float an = ea + fb1;
                float sg = 1.0f / (1.0f + expf(-an));
                float as = al * so1;
                float s5 = sg - 0.5f;
                float u1 = as + s5;
                float u2 = u1 + cx;
                float ts = th * sk1;
                float sn = u2 - ts;
                outf[n1]          = sn;
                outf[N_ + n1]     = ((sn - th) > 0.0f) ? 1.f : 0.f;
                outf[2 * N_ + n1] = an;
                outf[3 * N_ + n1] = bn;
            }
        }
        sk0 = sk0n; cv0 = cv0n; bt0 = bt0n; ac0 = ac0n; fb0 = fb0n; so0 = so0n;
        sk1 = sk1n; cv1 = cv1n; bt1 = bt1n; ac1 = ac1n; fb1 = fb1n; so1 = so1n;
        n += (size_t)(2 * CP_);
    }
}

extern "C" void kernel_launch(void* const* d_in, const int* in_sizes, int n_in,
                              void* d_out, int out_size, void* d_ws, size_t ws_size,
                              hipStream_t stream)
{
    const float* ff        = (const float*)d_in[0];
    const float* fb        = (const float*)d_in[1];
    const float* soma_t    = (const float*)d_in[2];
    const float* spk_t     = (const float*)d_in[3];
    const float* a_curr    = (const float*)d_in[4];
    const float* b_t       = (const float*)d_in[5];
    const float* weight    = (const float*)d_in[6];
    const float* conv_bias = (const float*)d_in[7];
    const float* local_rec = (const float*)d_in[8];
    const float* gamma     = (const float*)d_in[9];
    const float* beta      = (const float*)d_in[10];
    const float* tau_m     = (const float*)d_in[11];
    const float* tau_adp   = (const float*)d_in[12];
    const float* tau_a     = (const float*)d_in[13];

    // ws: f64 partials then Mb (~0.5 MB total)
    double* part_sum = (double*)d_ws;                       // NBLK_CONV*CO_
    double* part_sq  = part_sum + (size_t)NBLK_CONV * CO_;  // NBLK_CONV*CO_
    float*  Mb       = (float*)(part_sq + (size_t)NBLK_CONV * CO_);  // 64

    float* outf = (float*)d_out;

    conv_kernel<<<dim3(3840), 64, 0, stream>>>(
        ff, weight, conv_bias, outf, part_sum, part_sq);
    bn_finalize<<<dim3(CO_), 256, 0, stream>>>(part_sum, part_sq, Mb);
    lif_rec_kernel<<<dim3(512), 1024, 0, stream>>>(
        outf, local_rec, tau_m, tau_adp, tau_a, Mb, gamma, beta,
        fb, soma_t, spk_t, a_curr, b_t);
}